// Round 1
// baseline (401.031 us; speedup 1.0000x reference)
//
#include <hip/hip_runtime.h>

#define TAU  0.01f
#define EPSB 1e-8f
#define NEGV -1e9f

// Kernel 1: compute masked_logit, run iterative Gumbel top-K selection.
// One block of 64 threads (N = 64 patches).
__global__ void stk_select(const float* __restrict__ logit,
                           const float* __restrict__ bg,
                           const float* __restrict__ gumbel,
                           float* __restrict__ ml_out,   // 64 floats (output tail)
                           int*   __restrict__ sel_idx,  // K ints (workspace)
                           float* __restrict__ sel_w,    // K floats (workspace)
                           int K) {
    __shared__ float pv[64];
    __shared__ float mk[64];
    int t = threadIdx.x;

    float lm = logf(fmaxf(1.0f - bg[t], EPSB));
    float ml = logit[t] + lm;
    ml_out[t] = ml;                 // masked_logit output
    pv[t] = ml + gumbel[t];         // perturbed
    mk[t] = 0.0f;                   // accumulated mask
    __syncthreads();

    if (t == 0) {
        for (int k = 0; k < K; ++k) {
            // argmax of (perturbed + mask), first-occurrence tie-break like jnp.argmax
            int   best = 0;
            float bv   = pv[0] + mk[0];
            for (int j = 1; j < 64; ++j) {
                float v = pv[j] + mk[j];
                if (v > bv) { bv = v; best = j; }
            }
            // softmax value at argmax: 1 / sum_j exp((x_j - x_max)) with x = (p+m)/tau
            float xmax  = bv / TAU;
            float denom = 0.0f;
            for (int j = 0; j < 64; ++j) {
                float x = (pv[j] + mk[j]) / TAU;
                denom += expf(x - xmax);   // masked entries: exp(-1e11) -> 0
            }
            sel_idx[k] = best;
            sel_w[k]   = 1.0f / denom;
            mk[best]  += NEGV;
        }
    }
}

// Kernel 2: gather selected patches. One thread per float4 of output.
// Image region: [K,4,64,64,64] scaled by sel_w[k]; label region: [K,1,64,64,64].
__global__ void stk_gather(const float4* __restrict__ img,   // [4,256,256,256]
                           const float4* __restrict__ lab,   // [1,256,256,256]
                           float4* __restrict__ out,
                           const int*   __restrict__ sel_idx,
                           const float* __restrict__ sel_w,
                           int nImg4, int nTot4) {
    int tid = blockIdx.x * blockDim.x + threadIdx.x;
    if (tid >= nTot4) return;

    if (tid < nImg4) {
        // image: v = ((k*4 + c)*64 + hp)*64*16 + wp*16 + dp4
        int v   = tid;
        int dp4 = v & 15;
        int wp  = (v >> 4)  & 63;
        int hp  = (v >> 10) & 63;
        int c   = (v >> 16) & 3;
        int k   = v >> 18;
        int n   = sel_idx[k];
        int hn  = n >> 4, wn = (n >> 2) & 3, dn = n & 3;
        // src float4 index: c*256^3/4 + (hn*64+hp)*256^2/4 + (wn*64+wp)*256/4 + dn*16 + dp4
        int src = c * 4194304 + (hn * 64 + hp) * 16384 + (wn * 64 + wp) * 64 + dn * 16 + dp4;
        float4 d = img[src];
        float  w = sel_w[k];
        d.x *= w; d.y *= w; d.z *= w; d.w *= w;
        out[tid] = d;
    } else {
        int u   = tid - nImg4;
        int dp4 = u & 15;
        int wp  = (u >> 4)  & 63;
        int hp  = (u >> 10) & 63;
        int k   = u >> 16;
        int n   = sel_idx[k];
        int hn  = n >> 4, wn = (n >> 2) & 3, dn = n & 3;
        int src = (hn * 64 + hp) * 16384 + (wn * 64 + wp) * 64 + dn * 16 + dp4;
        out[tid] = lab[src];
    }
}

extern "C" void kernel_launch(void* const* d_in, const int* in_sizes, int n_in,
                              void* d_out, int out_size, void* d_ws, size_t ws_size,
                              hipStream_t stream) {
    const float* image  = (const float*)d_in[0];  // [1,4,256,256,256]
    const float* label  = (const float*)d_in[1];  // [1,1,256,256,256]
    const float* logit  = (const float*)d_in[2];  // [1,1,4,4,4]
    const float* bg     = (const float*)d_in[3];  // [1,1,4,4,4]
    const float* gumbel = (const float*)d_in[4];  // [1,64]
    // d_in[5] is k; derive K from out_size to keep it compile-time-independent:
    // out_size = K*(4+1)*64^3 + 64
    int K = (out_size - 64) / (5 * 64 * 64 * 64);

    float* out     = (float*)d_out;
    int*   sel_idx = (int*)d_ws;
    float* sel_w   = (float*)((char*)d_ws + 64);      // keep regions separated/aligned
    float* ml_out  = out + (size_t)K * 5 * 64 * 64 * 64 / 1 * 0 + (size_t)K * 1310720; // K*(4+1)*262144

    stk_select<<<1, 64, 0, stream>>>(logit, bg, gumbel, ml_out, sel_idx, sel_w, K);

    int nImg4 = K * 4 * 65536;        // K*4*262144/4
    int nTot4 = nImg4 + K * 65536;    // + K*262144/4
    int blocks = (nTot4 + 255) / 256;
    stk_gather<<<blocks, 256, 0, stream>>>((const float4*)image, (const float4*)label,
                                           (float4*)out, sel_idx, sel_w, nImg4, nTot4);
}

// Round 3
// 353.676 us; speedup vs baseline: 1.1339x; 1.1339x over previous
//
#include <hip/hip_runtime.h>

#define TAU_INV 100.0f
#define EPSB    1e-8f
#define NEGV    -1e9f

typedef float v4f __attribute__((ext_vector_type(4)));

// Kernel 1: masked_logit + iterative Gumbel top-K selection, fully parallel
// across one 64-lane wave (N = 64 patches).
__global__ void stk_select(const float* __restrict__ logit,
                           const float* __restrict__ bg,
                           const float* __restrict__ gumbel,
                           float* __restrict__ ml_out,   // 64 floats (output tail)
                           int*   __restrict__ sel_idx,  // K ints (workspace)
                           float* __restrict__ sel_w,    // K floats (workspace)
                           int K) {
    int t = threadIdx.x;  // 0..63, one wave

    float lm = logf(fmaxf(1.0f - bg[t], EPSB));
    float ml = logit[t] + lm;
    ml_out[t] = ml;                 // masked_logit output
    float pv = ml + gumbel[t];      // perturbed (register-resident)
    float mk = 0.0f;                // accumulated mask

    for (int k = 0; k < K; ++k) {
        float v   = pv + mk;
        // wave argmax (prefer lower index on ties, matching jnp.argmax)
        float bv  = v;
        int   bi  = t;
        #pragma unroll
        for (int off = 32; off >= 1; off >>= 1) {
            float vo = __shfl_xor(bv, off);
            int   io = __shfl_xor(bi, off);
            if (vo > bv || (vo == bv && io < bi)) { bv = vo; bi = io; }
        }
        // parallel softmax denominator: sum_j exp((v_j - bv)/tau)
        float e = __expf((v - bv) * TAU_INV);   // masked lanes -> exp(-1e11) = 0
        #pragma unroll
        for (int off = 32; off >= 1; off >>= 1)
            e += __shfl_xor(e, off);

        if (t == 0) {
            sel_idx[k] = bi;
            sel_w[k]   = 1.0f / e;
        }
        if (t == bi) mk += NEGV;
    }
}

// Kernel 2: gather selected patches, one thread per float4 of output.
// Image region: [K,4,64,64,64] scaled by sel_w[k]; label region: [K,1,64,64,64].
__global__ void stk_gather(const v4f* __restrict__ img,   // [4,256,256,256]
                           const v4f* __restrict__ lab,   // [1,256,256,256]
                           v4f* __restrict__ out,
                           const int*   __restrict__ sel_idx,
                           const float* __restrict__ sel_w,
                           int nImg4, int nTot4) {
    int tid = blockIdx.x * blockDim.x + threadIdx.x;
    if (tid >= nTot4) return;

    if (tid < nImg4) {
        int v   = tid;
        int dp4 = v & 15;
        int wp  = (v >> 4)  & 63;
        int hp  = (v >> 10) & 63;
        int c   = (v >> 16) & 3;
        int k   = v >> 18;
        int n   = sel_idx[k];
        int hn  = n >> 4, wn = (n >> 2) & 3, dn = n & 3;
        int src = c * 4194304 + (hn * 64 + hp) * 16384 + (wn * 64 + wp) * 64 + dn * 16 + dp4;
        v4f d = __builtin_nontemporal_load(&img[src]);
        float w = sel_w[k];
        d *= w;
        __builtin_nontemporal_store(d, &out[tid]);
    } else {
        int u   = tid - nImg4;
        int dp4 = u & 15;
        int wp  = (u >> 4)  & 63;
        int hp  = (u >> 10) & 63;
        int k   = u >> 16;
        int n   = sel_idx[k];
        int hn  = n >> 4, wn = (n >> 2) & 3, dn = n & 3;
        int src = (hn * 64 + hp) * 16384 + (wn * 64 + wp) * 64 + dn * 16 + dp4;
        v4f d = __builtin_nontemporal_load(&lab[src]);
        __builtin_nontemporal_store(d, &out[tid]);
    }
}

extern "C" void kernel_launch(void* const* d_in, const int* in_sizes, int n_in,
                              void* d_out, int out_size, void* d_ws, size_t ws_size,
                              hipStream_t stream) {
    const float* image  = (const float*)d_in[0];  // [1,4,256,256,256]
    const float* label  = (const float*)d_in[1];  // [1,1,256,256,256]
    const float* logit  = (const float*)d_in[2];  // [1,1,4,4,4]
    const float* bg     = (const float*)d_in[3];  // [1,1,4,4,4]
    const float* gumbel = (const float*)d_in[4];  // [1,64]
    // out_size = K*(4+1)*64^3 + 64
    int K = (out_size - 64) / (5 * 64 * 64 * 64);

    float* out     = (float*)d_out;
    int*   sel_idx = (int*)d_ws;
    float* sel_w   = (float*)((char*)d_ws + 64);
    float* ml_out  = out + (size_t)K * 1310720;   // K*(4+1)*262144

    stk_select<<<1, 64, 0, stream>>>(logit, bg, gumbel, ml_out, sel_idx, sel_w, K);

    int nImg4 = K * 4 * 65536;
    int nTot4 = nImg4 + K * 65536;
    int blocks = (nTot4 + 255) / 256;
    stk_gather<<<blocks, 256, 0, stream>>>((const v4f*)image, (const v4f*)label,
                                           (v4f*)out, sel_idx, sel_w, nImg4, nTot4);
}